// Round 7
// baseline (6096.561 us; speedup 1.0000x reference)
//
#include <hip/hip_runtime.h>
#include <hip/hip_bf16.h>

// RNN_46548855554081: 2-layer tanh RNN, B=64, T=512, H=1024, IN=64, OUT=1.
// Strategy: single persistent kernel, 4 batch-groups x 64 CUs, pipelined layers,
// 513 software-barrier steps, weights fp16 in registers, h fp16 in ws (tiled).
// fp16 (not bf16): 10-bit mantissa keeps recurrence error ~3e-3 << 1.47e-2 thr.
// Barrier spin is BOUNDED (2^20 polls): a deadlock degrades to wrong-answer,
// never a hung container.

typedef float f32x4 __attribute__((ext_vector_type(4)));
typedef _Float16 half8 __attribute__((ext_vector_type(8)));

#define T_STEPS 512
#define STEPS 513

// ws layout (bytes)
#define CTR_OFF   0                        // 4 counters, 256B apart (zeroed by prep_h)
#define XT_OFF    4096                     // [512][4][8kg][16row][8] f16 = 4 MB
#define H1_OFF    (XT_OFF + 4194304)       // [2buf][4g][128kg][16row][8] f16 = 256 KB
#define H2_OFF    (H1_OFF + 262144)        // same, 256 KB
#define H2T0_OFF  (H2_OFF + 262144)        // [64][1024] f32 = 256 KB (h2 at t=0)

__device__ inline float tanh_fast(float z) {
  z = fminf(20.f, fmaxf(-20.f, z));
  float e = __expf(2.f * z);
  return (e - 1.f) / (e + 1.f);
}

__device__ inline half8 ldw8(const float* p) {
  half8 r;
#pragma unroll
  for (int i = 0; i < 8; ++i) r[i] = (_Float16)p[i];
  return r;
}

// ---- prep: tile x into f16 fragment layout [t][g][kg(8)][16row][8] ----
__global__ void prep_x(const float* __restrict__ x, _Float16* __restrict__ xt) {
  int i = blockIdx.x * 256 + threadIdx.x;       // 2^21 elements
  int j = i & 7;
  int row = (i >> 3) & 15;
  int kgv = (i >> 7) & 7;
  int gg = (i >> 10) & 3;
  int t = i >> 12;
  int b = gg * 16 + row;
  xt[i] = (_Float16)x[(b * 512 + t) * 64 + kgv * 8 + j];
}

// ---- prep: tile h_state into h buffers (buf index 1), zero barrier counters ----
__global__ void prep_h(const float* __restrict__ hs, _Float16* __restrict__ h1b,
                       _Float16* __restrict__ h2b, char* __restrict__ wsbase) {
  int i = blockIdx.x * 256 + threadIdx.x;       // 2^17 elements
  int j = i & 7;
  int row = (i >> 3) & 15;
  int kgv = (i >> 7) & 127;
  int gg = (i >> 14) & 3;
  int l = i >> 16;
  int b = gg * 16 + row;
  int h = kgv * 8 + j;
  float v = hs[(size_t)l * 65536 + b * 1024 + h];
  _Float16* dst = l ? h2b : h1b;
  dst[(size_t)(4 + gg) * 16384 + (kgv * 16 + row) * 8 + j] = (_Float16)v;
  if (i < 4) *(unsigned*)(wsbase + CTR_OFF + (size_t)i * 256) = 0u;
}

// ---- persistent pipelined scan ----
__global__ __launch_bounds__(256, 1) void rnn_persist(
    const float* __restrict__ Wih0, const float* __restrict__ Whh0,
    const float* __restrict__ bih0, const float* __restrict__ bhh0,
    const float* __restrict__ Wih1, const float* __restrict__ Whh1,
    const float* __restrict__ bih1, const float* __restrict__ bhh1,
    const float* __restrict__ Wout, const float* __restrict__ bout,
    float* __restrict__ out, char* __restrict__ ws) {
  __shared__ float pcL1[256];
  __shared__ float pcL2[256];

  const int bid = blockIdx.x;
  const int g = bid >> 6;          // batch group (16 batches)
  const int cu = bid & 63;         // owns columns [16cu, 16cu+16) of both layers
  const int tid = threadIdx.x;
  const int wave = tid >> 6;
  const int lane = tid & 63;
  const int col = lane & 15;
  const int kg = lane >> 4;        // k-subgroup within fragment / row-group in C

  unsigned* ctr = (unsigned*)(ws + CTR_OFF + (size_t)g * 256);
  const _Float16* xt = (const _Float16*)(ws + XT_OFF);
  _Float16* h1b = (_Float16*)(ws + H1_OFF);
  _Float16* h2b = (_Float16*)(ws + H2_OFF);
  float* h2t0 = (float*)(ws + H2T0_OFF);

  const int c = cu * 16 + col;     // output column for this lane (B-frag / bias / store)

  // ---- weights -> f16 register fragments (once) ----
  // wave0: L1 K[0,544)   (x part K<64, then W_hh0)   17 frags
  // wave1: L1 K[544,1088)                            17 frags
  // wave2: L2 K[0,1024)  = W_ih1                     32 frags
  // wave3: L2 K[1024,2048) = W_hh1                   32 frags
  half8 bw[32];
  float bias = 0.f;
  if (wave == 0) {
#pragma unroll
    for (int f = 0; f < 17; ++f) {
      int k0 = f * 32 + kg * 8;
      const float* p = (k0 < 64) ? (Wih0 + c * 64 + k0) : (Whh0 + c * 1024 + (k0 - 64));
      bw[f] = ldw8(p);
    }
    bias = bih0[c] + bhh0[c];
  } else if (wave == 1) {
#pragma unroll
    for (int f = 0; f < 17; ++f) {
      int k0 = (f + 17) * 32 + kg * 8 - 64;   // [480, 1024)
      bw[f] = ldw8(Whh0 + c * 1024 + k0);
    }
  } else if (wave == 2) {
#pragma unroll
    for (int f = 0; f < 32; ++f) {
      int k0 = f * 32 + kg * 8;
      bw[f] = ldw8(Wih1 + c * 1024 + k0);
    }
    bias = bih1[c] + bhh1[c];
  } else {
#pragma unroll
    for (int f = 0; f < 32; ++f) {
      int k0 = f * 32 + kg * 8;
      bw[f] = ldw8(Whh1 + c * 1024 + k0);
    }
  }

  for (int s = 0; s < STEPS; ++s) {
    const bool l1act = (s < T_STEPS);   // computes h1[s]
    const bool l2act = (s >= 1);        // computes h2[s-1] from r1[s-1], h2[s-2]
    const _Float16* h1rd = h1b + (size_t)(((s + 1) & 1) * 4 + g) * 16384;  // h1[s-1]
    const _Float16* h2rd = h2b + (size_t)(((s) & 1) * 4 + g) * 16384;      // h2[s-2]
    _Float16* h1wr = h1b + (size_t)(((s) & 1) * 4 + g) * 16384;            // h1[s]
    _Float16* h2wr = h2b + (size_t)(((s + 1) & 1) * 4 + g) * 16384;        // h2[s-1]

    f32x4 acc = {0.f, 0.f, 0.f, 0.f};
    if (wave == 0) {
      if (l1act) {
        const _Float16* xsrc = xt + (size_t)(s * 4 + g) * 1024;
#pragma unroll
        for (int f = 0; f < 17; ++f) {
          const _Float16* ap = (f < 2) ? (xsrc + f * 512) : (h1rd + (f - 2) * 512);
          half8 a = *(const half8*)(ap + lane * 8);
          acc = __builtin_amdgcn_mfma_f32_16x16x32_f16(a, bw[f], acc, 0, 0, 0);
        }
      }
    } else if (wave == 1) {
      if (l1act) {
#pragma unroll
        for (int f = 0; f < 17; ++f) {
          half8 a = *(const half8*)(h1rd + (f + 15) * 512 + lane * 8);
          acc = __builtin_amdgcn_mfma_f32_16x16x32_f16(a, bw[f], acc, 0, 0, 0);
        }
#pragma unroll
        for (int r = 0; r < 4; ++r) pcL1[(kg * 4 + r) * 16 + col] = acc[r];
      }
    } else if (wave == 2) {
      if (l2act) {
#pragma unroll
        for (int f = 0; f < 32; ++f) {
          half8 a = *(const half8*)(h1rd + f * 512 + lane * 8);
          acc = __builtin_amdgcn_mfma_f32_16x16x32_f16(a, bw[f], acc, 0, 0, 0);
        }
      }
    } else {
      if (l2act) {
#pragma unroll
        for (int f = 0; f < 32; ++f) {
          half8 a = *(const half8*)(h2rd + f * 512 + lane * 8);
          acc = __builtin_amdgcn_mfma_f32_16x16x32_f16(a, bw[f], acc, 0, 0, 0);
        }
#pragma unroll
        for (int r = 0; r < 4; ++r) pcL2[(kg * 4 + r) * 16 + col] = acc[r];
      }
    }
    __syncthreads();

    if (wave == 0 && l1act) {
#pragma unroll
      for (int r = 0; r < 4; ++r) {
        int row = kg * 4 + r;
        float z = acc[r] + pcL1[row * 16 + col] + bias;
        float h = tanh_fast(z);
        h1wr[((cu * 2 + (col >> 3)) * 16 + row) * 8 + (col & 7)] = (_Float16)h;
        if (s == T_STEPS - 1) out[64 + (g * 16 + row) * 1024 + c] = h;  // h_new[0]
      }
    }
    if (wave == 2 && l2act) {
#pragma unroll
      for (int r = 0; r < 4; ++r) {
        int row = kg * 4 + r;
        float z = acc[r] + pcL2[row * 16 + col] + bias;
        float h = tanh_fast(z);
        h2wr[((cu * 2 + (col >> 3)) * 16 + row) * 8 + (col & 7)] = (_Float16)h;
        if (s == 1) h2t0[(size_t)(g * 16 + row) * 1024 + c] = h;        // r2[:,0,:]
        if (s == STEPS - 1) out[64 + 65536 + (g * 16 + row) * 1024 + c] = h;  // h_new[1]
      }
    }
    __syncthreads();

    // group barrier: monotonic counter, agent-scope release/acquire.
    // Spin is bounded: normal wait ~400 polls; cap 2^20 (~0.13s) means a
    // deadlock produces a wrong answer + diagnosable absmax, not a hang.
    if (tid == 0) {
      __builtin_amdgcn_fence(__ATOMIC_RELEASE, "agent");
      __hip_atomic_fetch_add(ctr, 1u, __ATOMIC_RELAXED, __HIP_MEMORY_SCOPE_AGENT);
      const unsigned target = 64u * (unsigned)(s + 1);
      unsigned spins = 0;
      while (__hip_atomic_load(ctr, __ATOMIC_RELAXED, __HIP_MEMORY_SCOPE_AGENT) < target) {
        __builtin_amdgcn_s_sleep(2);
        if (++spins > (1u << 20)) break;   // safety valve
      }
      __builtin_amdgcn_fence(__ATOMIC_ACQUIRE, "agent");
    }
    __syncthreads();
  }

  // out = r2[:,0,:] @ W_out^T + b_out  (leader WG of each group: its 16 batches)
  if (cu == 0) {
    const int b = tid >> 4, seg = tid & 15;
    const float* hrow = h2t0 + (size_t)(g * 16 + b) * 1024 + seg * 64;
    const float* wrow = Wout + seg * 64;
    float sum = 0.f;
#pragma unroll
    for (int i = 0; i < 64; ++i) sum += hrow[i] * wrow[i];
    sum += __shfl_xor(sum, 1);
    sum += __shfl_xor(sum, 2);
    sum += __shfl_xor(sum, 4);
    sum += __shfl_xor(sum, 8);
    if (seg == 0) out[g * 16 + b] = sum + bout[0];
  }
}

extern "C" void kernel_launch(void* const* d_in, const int* in_sizes, int n_in,
                              void* d_out, int out_size, void* d_ws, size_t ws_size,
                              hipStream_t stream) {
  const float* x    = (const float*)d_in[0];
  const float* hs   = (const float*)d_in[1];
  const float* Wih0 = (const float*)d_in[2];
  const float* Whh0 = (const float*)d_in[3];
  const float* bih0 = (const float*)d_in[4];
  const float* bhh0 = (const float*)d_in[5];
  const float* Wih1 = (const float*)d_in[6];
  const float* Whh1 = (const float*)d_in[7];
  const float* bih1 = (const float*)d_in[8];
  const float* bhh1 = (const float*)d_in[9];
  const float* Wout = (const float*)d_in[10];
  const float* bout = (const float*)d_in[11];
  float* out = (float*)d_out;
  char* ws = (char*)d_ws;

  _Float16* xt  = (_Float16*)(ws + XT_OFF);
  _Float16* h1b = (_Float16*)(ws + H1_OFF);
  _Float16* h2b = (_Float16*)(ws + H2_OFF);

  prep_x<<<8192, 256, 0, stream>>>(x, xt);
  prep_h<<<512, 256, 0, stream>>>(hs, h1b, h2b, ws);
  rnn_persist<<<256, 256, 0, stream>>>(Wih0, Whh0, bih0, bhh0,
                                       Wih1, Whh1, bih1, bhh1,
                                       Wout, bout, out, ws);
}

// Round 9
// 5717.561 us; speedup vs baseline: 1.0663x; 1.0663x over previous
//
#include <hip/hip_runtime.h>
#include <hip/hip_bf16.h>

// RNN_46548855554081: 2-layer tanh RNN, B=64, T=512, H=1024, IN=64, OUT=1.
// R9 = R7's measured-good structure (256 WGs x 256 thr, 104 VGPR, fp16 weights
// in regs, pipelined layers, absmax 1.95e-3) with ONLY the barrier replaced:
// R7 counters showed 11.9us/step, ~10.5us = 64-way serialized agent-RMW chain.
// Now: per-WG FLAG STORE (parallel, no RMW) + wave0 64-lane gather-poll.

typedef float f32x4 __attribute__((ext_vector_type(4)));
typedef _Float16 half8 __attribute__((ext_vector_type(8)));

#define T_STEPS 512
#define STEPS 513

// ws layout (bytes)
#define CTR_OFF   0                        // 256 flag slots x 64B = 16KB (zeroed by prep_h)
#define XT_OFF    16384                    // [512][4][8kg][16row][8] f16 = 4 MB
#define H1_OFF    (XT_OFF + 4194304)       // [2buf][4g][128kg][16row][8] f16 = 256 KB
#define H2_OFF    (H1_OFF + 262144)        // same, 256 KB
#define H2T0_OFF  (H2_OFF + 262144)        // [64][1024] f32 = 256 KB (h2 at t=0)

__device__ inline float tanh_fast(float z) {
  z = fminf(20.f, fmaxf(-20.f, z));
  float e = __expf(2.f * z);
  return (e - 1.f) / (e + 1.f);
}

__device__ inline half8 ldw8(const float* p) {
  half8 r;
#pragma unroll
  for (int i = 0; i < 8; ++i) r[i] = (_Float16)p[i];
  return r;
}

// ---- prep: tile x into f16 fragment layout [t][g][kg(8)][16row][8] ----
__global__ void prep_x(const float* __restrict__ x, _Float16* __restrict__ xt) {
  int i = blockIdx.x * 256 + threadIdx.x;       // 2^21 elements
  int j = i & 7;
  int row = (i >> 3) & 15;
  int kgv = (i >> 7) & 7;
  int gg = (i >> 10) & 3;
  int t = i >> 12;
  int b = gg * 16 + row;
  xt[i] = (_Float16)x[(b * 512 + t) * 64 + kgv * 8 + j];
}

// ---- prep: tile h_state into h buffers (buf index 1), zero barrier flags ----
__global__ void prep_h(const float* __restrict__ hs, _Float16* __restrict__ h1b,
                       _Float16* __restrict__ h2b, char* __restrict__ wsbase) {
  int i = blockIdx.x * 256 + threadIdx.x;       // 2^17 elements
  int j = i & 7;
  int row = (i >> 3) & 15;
  int kgv = (i >> 7) & 127;
  int gg = (i >> 14) & 3;
  int l = i >> 16;
  int b = gg * 16 + row;
  int h = kgv * 8 + j;
  float v = hs[(size_t)l * 65536 + b * 1024 + h];
  _Float16* dst = l ? h2b : h1b;
  dst[(size_t)(4 + gg) * 16384 + (kgv * 16 + row) * 8 + j] = (_Float16)v;
  if (i < 256) *(unsigned*)(wsbase + CTR_OFF + (size_t)i * 64) = 0u;
}

// ---- persistent pipelined scan ----
__global__ __launch_bounds__(256, 1) void rnn_persist(
    const float* __restrict__ Wih0, const float* __restrict__ Whh0,
    const float* __restrict__ bih0, const float* __restrict__ bhh0,
    const float* __restrict__ Wih1, const float* __restrict__ Whh1,
    const float* __restrict__ bih1, const float* __restrict__ bhh1,
    const float* __restrict__ Wout, const float* __restrict__ bout,
    float* __restrict__ out, char* __restrict__ ws) {
  __shared__ float pcL1[256];
  __shared__ float pcL2[256];

  const int bid = blockIdx.x;
  const int g = bid >> 6;          // batch group (16 batches)
  const int cu = bid & 63;         // owns columns [16cu, 16cu+16) of both layers
  const int tid = threadIdx.x;
  const int wave = tid >> 6;
  const int lane = tid & 63;
  const int col = lane & 15;
  const int kg = lane >> 4;        // k-subgroup within fragment / row-group in C

  unsigned* flags = (unsigned*)(ws + CTR_OFF);   // slot (g*64+cu), 64B stride
  const _Float16* xt = (const _Float16*)(ws + XT_OFF);
  _Float16* h1b = (_Float16*)(ws + H1_OFF);
  _Float16* h2b = (_Float16*)(ws + H2_OFF);
  float* h2t0 = (float*)(ws + H2T0_OFF);

  const int c = cu * 16 + col;     // output column for this lane (B-frag / bias / store)

  // ---- weights -> f16 register fragments (once) ----
  // wave0: L1 K[0,544)   (x part K<64, then W_hh0)   17 frags
  // wave1: L1 K[544,1088)                            17 frags
  // wave2: L2 K[0,1024)  = W_ih1                     32 frags
  // wave3: L2 K[1024,2048) = W_hh1                   32 frags
  half8 bw[32];
  float bias = 0.f;
  if (wave == 0) {
#pragma unroll
    for (int f = 0; f < 17; ++f) {
      int k0 = f * 32 + kg * 8;
      const float* p = (k0 < 64) ? (Wih0 + c * 64 + k0) : (Whh0 + c * 1024 + (k0 - 64));
      bw[f] = ldw8(p);
    }
    bias = bih0[c] + bhh0[c];
  } else if (wave == 1) {
#pragma unroll
    for (int f = 0; f < 17; ++f) {
      int k0 = (f + 17) * 32 + kg * 8 - 64;   // [480, 1024)
      bw[f] = ldw8(Whh0 + c * 1024 + k0);
    }
  } else if (wave == 2) {
#pragma unroll
    for (int f = 0; f < 32; ++f) {
      int k0 = f * 32 + kg * 8;
      bw[f] = ldw8(Wih1 + c * 1024 + k0);
    }
    bias = bih1[c] + bhh1[c];
  } else {
#pragma unroll
    for (int f = 0; f < 32; ++f) {
      int k0 = f * 32 + kg * 8;
      bw[f] = ldw8(Whh1 + c * 1024 + k0);
    }
  }

  for (int s = 0; s < STEPS; ++s) {
    const bool l1act = (s < T_STEPS);   // computes h1[s]
    const bool l2act = (s >= 1);        // computes h2[s-1] from r1[s-1], h2[s-2]
    const _Float16* h1rd = h1b + (size_t)(((s + 1) & 1) * 4 + g) * 16384;  // h1[s-1]
    const _Float16* h2rd = h2b + (size_t)(((s) & 1) * 4 + g) * 16384;      // h2[s-2]
    _Float16* h1wr = h1b + (size_t)(((s) & 1) * 4 + g) * 16384;            // h1[s]
    _Float16* h2wr = h2b + (size_t)(((s + 1) & 1) * 4 + g) * 16384;        // h2[s-1]

    f32x4 acc = {0.f, 0.f, 0.f, 0.f};
    if (wave == 0) {
      if (l1act) {
        const _Float16* xsrc = xt + (size_t)(s * 4 + g) * 1024;
#pragma unroll
        for (int f = 0; f < 17; ++f) {
          const _Float16* ap = (f < 2) ? (xsrc + f * 512) : (h1rd + (f - 2) * 512);
          half8 a = *(const half8*)(ap + lane * 8);
          acc = __builtin_amdgcn_mfma_f32_16x16x32_f16(a, bw[f], acc, 0, 0, 0);
        }
      }
    } else if (wave == 1) {
      if (l1act) {
#pragma unroll
        for (int f = 0; f < 17; ++f) {
          half8 a = *(const half8*)(h1rd + (f + 15) * 512 + lane * 8);
          acc = __builtin_amdgcn_mfma_f32_16x16x32_f16(a, bw[f], acc, 0, 0, 0);
        }
#pragma unroll
        for (int r = 0; r < 4; ++r) pcL1[(kg * 4 + r) * 16 + col] = acc[r];
      }
    } else if (wave == 2) {
      if (l2act) {
#pragma unroll
        for (int f = 0; f < 32; ++f) {
          half8 a = *(const half8*)(h1rd + f * 512 + lane * 8);
          acc = __builtin_amdgcn_mfma_f32_16x16x32_f16(a, bw[f], acc, 0, 0, 0);
        }
      }
    } else {
      if (l2act) {
#pragma unroll
        for (int f = 0; f < 32; ++f) {
          half8 a = *(const half8*)(h2rd + f * 512 + lane * 8);
          acc = __builtin_amdgcn_mfma_f32_16x16x32_f16(a, bw[f], acc, 0, 0, 0);
        }
#pragma unroll
        for (int r = 0; r < 4; ++r) pcL2[(kg * 4 + r) * 16 + col] = acc[r];
      }
    }
    __syncthreads();

    if (wave == 0 && l1act) {
#pragma unroll
      for (int r = 0; r < 4; ++r) {
        int row = kg * 4 + r;
        float z = acc[r] + pcL1[row * 16 + col] + bias;
        float h = tanh_fast(z);
        h1wr[((cu * 2 + (col >> 3)) * 16 + row) * 8 + (col & 7)] = (_Float16)h;
        if (s == T_STEPS - 1) out[64 + (g * 16 + row) * 1024 + c] = h;  // h_new[0]
      }
    }
    if (wave == 2 && l2act) {
#pragma unroll
      for (int r = 0; r < 4; ++r) {
        int row = kg * 4 + r;
        float z = acc[r] + pcL2[row * 16 + col] + bias;
        float h = tanh_fast(z);
        h2wr[((cu * 2 + (col >> 3)) * 16 + row) * 8 + (col & 7)] = (_Float16)h;
        if (s == 1) h2t0[(size_t)(g * 16 + row) * 1024 + c] = h;        // r2[:,0,:]
        if (s == STEPS - 1) out[64 + 65536 + (g * 16 + row) * 1024 + c] = h;  // h_new[1]
      }
    }
    __syncthreads();   // all h stores drained (compiler emits vmcnt(0) before barrier)

    // ---- group barrier: parallel per-WG flag stores + 64-lane gather-poll ----
    // No RMW chain (R7's measured 10.5us/step cost): 64 stores to 64 distinct
    // lines proceed in parallel; wave0 lane L polls WG L's flag. Flags are
    // monotonic (store s+1, poll >= s+1): no reset, no ABA. Bounded spin:
    // a deadlock degrades to wrong-answer, never a hung container.
    if (tid == 0) {
      __builtin_amdgcn_fence(__ATOMIC_RELEASE, "agent");
      __hip_atomic_store(flags + (size_t)(g * 64 + cu) * 16, (unsigned)(s + 1),
                         __ATOMIC_RELAXED, __HIP_MEMORY_SCOPE_AGENT);
    }
    if (tid < 64) {
      unsigned* f = flags + (size_t)(g * 64 + tid) * 16;
      unsigned spins = 0;
      while (__hip_atomic_load(f, __ATOMIC_RELAXED, __HIP_MEMORY_SCOPE_AGENT) <
             (unsigned)(s + 1)) {
        __builtin_amdgcn_s_sleep(1);
        if (++spins > (1u << 20)) break;   // safety valve
      }
    }
    __syncthreads();
    if (tid == 0) __builtin_amdgcn_fence(__ATOMIC_ACQUIRE, "agent");
    __syncthreads();
  }

  // out = r2[:,0,:] @ W_out^T + b_out  (leader WG of each group: its 16 batches)
  if (cu == 0) {
    const int b = tid >> 4, seg = tid & 15;
    const float* hrow = h2t0 + (size_t)(g * 16 + b) * 1024 + seg * 64;
    const float* wrow = Wout + seg * 64;
    float sum = 0.f;
#pragma unroll
    for (int i = 0; i < 64; ++i) sum += hrow[i] * wrow[i];
    sum += __shfl_xor(sum, 1);
    sum += __shfl_xor(sum, 2);
    sum += __shfl_xor(sum, 4);
    sum += __shfl_xor(sum, 8);
    if (seg == 0) out[g * 16 + b] = sum + bout[0];
  }
}

extern "C" void kernel_launch(void* const* d_in, const int* in_sizes, int n_in,
                              void* d_out, int out_size, void* d_ws, size_t ws_size,
                              hipStream_t stream) {
  const float* x    = (const float*)d_in[0];
  const float* hs   = (const float*)d_in[1];
  const float* Wih0 = (const float*)d_in[2];
  const float* Whh0 = (const float*)d_in[3];
  const float* bih0 = (const float*)d_in[4];
  const float* bhh0 = (const float*)d_in[5];
  const float* Wih1 = (const float*)d_in[6];
  const float* Whh1 = (const float*)d_in[7];
  const float* bih1 = (const float*)d_in[8];
  const float* bhh1 = (const float*)d_in[9];
  const float* Wout = (const float*)d_in[10];
  const float* bout = (const float*)d_in[11];
  float* out = (float*)d_out;
  char* ws = (char*)d_ws;

  _Float16* xt  = (_Float16*)(ws + XT_OFF);
  _Float16* h1b = (_Float16*)(ws + H1_OFF);
  _Float16* h2b = (_Float16*)(ws + H2_OFF);

  prep_x<<<8192, 256, 0, stream>>>(x, xt);
  prep_h<<<512, 256, 0, stream>>>(hs, h1b, h2b, ws);
  rnn_persist<<<256, 256, 0, stream>>>(Wih0, Whh0, bih0, bhh0,
                                       Wih1, Whh1, bih1, bhh1,
                                       Wout, bout, out, ws);
}

// Round 11
// 2574.767 us; speedup vs baseline: 2.3678x; 2.2206x over previous
//
#include <hip/hip_runtime.h>
#include <hip/hip_bf16.h>

// RNN_46548855554081: 2-layer tanh RNN, B=64, T=512, H=1024, IN=64, OUT=1.
// R10: FENCE-FREE coherence. R7 vs R9 proved the barrier RMW chain was NOT the
// ~11us/step cost; the invariant suspects are the per-WG per-step agent fences
// (buffer_wbl2 + buffer_inv = full L2 walks) and their refetch fallout
// (FETCH_SIZE 541MB). Now: h state moves via RELAXED AGENT-SCOPE ATOMICS
// (sc0 sc1, write-through/read-through the die coherence point) -> no fences
// at all. Flag barrier: parallel per-WG stores + 64-lane gather poll (R9).
// Structure/numerics identical to R7/R9 (absmax 1.95e-3 both).

typedef float f32x4 __attribute__((ext_vector_type(4)));
typedef _Float16 half8 __attribute__((ext_vector_type(8)));

#define T_STEPS 512
#define STEPS 513

// ws layout (bytes)
#define CTR_OFF   0                        // 256 flag slots x 64B = 16KB (zeroed by prep_h)
#define XT_OFF    16384                    // [512][4][8kg][16row][8] f16 = 4 MB
#define H1_OFF    (XT_OFF + 4194304)       // [2buf][4g][128kg][16row][8] f16 = 256 KB
#define H2_OFF    (H1_OFF + 262144)        // same, 256 KB
#define H2T0_OFF  (H2_OFF + 262144)        // [64][1024] f32 = 256 KB (h2 at t=0)

__device__ inline float tanh_fast(float z) {
  z = fminf(20.f, fmaxf(-20.f, z));
  float e = __expf(2.f * z);
  return (e - 1.f) / (e + 1.f);
}

__device__ inline half8 ldw8(const float* p) {
  half8 r;
#pragma unroll
  for (int i = 0; i < 8; ++i) r[i] = (_Float16)p[i];
  return r;
}

// coherent (agent-scope, relaxed) 16B fragment load: 2 x u64 atomic loads
__device__ inline half8 ldh8_coh(const _Float16* p) {
  union { unsigned long long q[2]; half8 h; } u;
  unsigned long long* a = (unsigned long long*)p;
  u.q[0] = __hip_atomic_load(a,     __ATOMIC_RELAXED, __HIP_MEMORY_SCOPE_AGENT);
  u.q[1] = __hip_atomic_load(a + 1, __ATOMIC_RELAXED, __HIP_MEMORY_SCOPE_AGENT);
  return u.h;
}

// coherent 2B h-element store
__device__ inline void sth_coh(_Float16* p, float v) {
  union { _Float16 h; unsigned short u; } cv;
  cv.h = (_Float16)v;
  __hip_atomic_store((unsigned short*)p, cv.u, __ATOMIC_RELAXED, __HIP_MEMORY_SCOPE_AGENT);
}

// ---- prep: tile x into f16 fragment layout [t][g][kg(8)][16row][8] ----
__global__ void prep_x(const float* __restrict__ x, _Float16* __restrict__ xt) {
  int i = blockIdx.x * 256 + threadIdx.x;       // 2^21 elements
  int j = i & 7;
  int row = (i >> 3) & 15;
  int kgv = (i >> 7) & 7;
  int gg = (i >> 10) & 3;
  int t = i >> 12;
  int b = gg * 16 + row;
  xt[i] = (_Float16)x[(b * 512 + t) * 64 + kgv * 8 + j];
}

// ---- prep: tile h_state into h buffers (buf index 1), zero barrier flags ----
__global__ void prep_h(const float* __restrict__ hs, _Float16* __restrict__ h1b,
                       _Float16* __restrict__ h2b, char* __restrict__ wsbase) {
  int i = blockIdx.x * 256 + threadIdx.x;       // 2^17 elements
  int j = i & 7;
  int row = (i >> 3) & 15;
  int kgv = (i >> 7) & 127;
  int gg = (i >> 14) & 3;
  int l = i >> 16;
  int b = gg * 16 + row;
  int h = kgv * 8 + j;
  float v = hs[(size_t)l * 65536 + b * 1024 + h];
  _Float16* dst = l ? h2b : h1b;
  dst[(size_t)(4 + gg) * 16384 + (kgv * 16 + row) * 8 + j] = (_Float16)v;
  if (i < 256) *(unsigned*)(wsbase + CTR_OFF + (size_t)i * 64) = 0u;
}

// ---- persistent pipelined scan ----
__global__ __launch_bounds__(256, 1) void rnn_persist(
    const float* __restrict__ Wih0, const float* __restrict__ Whh0,
    const float* __restrict__ bih0, const float* __restrict__ bhh0,
    const float* __restrict__ Wih1, const float* __restrict__ Whh1,
    const float* __restrict__ bih1, const float* __restrict__ bhh1,
    const float* __restrict__ Wout, const float* __restrict__ bout,
    float* __restrict__ out, char* __restrict__ ws) {
  __shared__ float pcL1[256];
  __shared__ float pcL2[256];

  const int bid = blockIdx.x;
  const int g = bid >> 6;          // batch group (16 batches)
  const int cu = bid & 63;         // owns columns [16cu, 16cu+16) of both layers
  const int tid = threadIdx.x;
  const int wave = tid >> 6;
  const int lane = tid & 63;
  const int col = lane & 15;
  const int kg = lane >> 4;        // k-subgroup within fragment / row-group in C

  unsigned* flags = (unsigned*)(ws + CTR_OFF);   // slot (g*64+cu), 64B stride
  const _Float16* xt = (const _Float16*)(ws + XT_OFF);
  _Float16* h1b = (_Float16*)(ws + H1_OFF);
  _Float16* h2b = (_Float16*)(ws + H2_OFF);
  float* h2t0 = (float*)(ws + H2T0_OFF);

  const int c = cu * 16 + col;     // output column for this lane (B-frag / bias / store)

  // ---- weights -> f16 register fragments (once) ----
  // wave0: L1 K[0,544)   (x part K<64, then W_hh0)   17 frags
  // wave1: L1 K[544,1088)                            17 frags
  // wave2: L2 K[0,1024)  = W_ih1                     32 frags
  // wave3: L2 K[1024,2048) = W_hh1                   32 frags
  half8 bw[32];
  float bias = 0.f;
  if (wave == 0) {
#pragma unroll
    for (int f = 0; f < 17; ++f) {
      int k0 = f * 32 + kg * 8;
      const float* p = (k0 < 64) ? (Wih0 + c * 64 + k0) : (Whh0 + c * 1024 + (k0 - 64));
      bw[f] = ldw8(p);
    }
    bias = bih0[c] + bhh0[c];
  } else if (wave == 1) {
#pragma unroll
    for (int f = 0; f < 17; ++f) {
      int k0 = (f + 17) * 32 + kg * 8 - 64;   // [480, 1024)
      bw[f] = ldw8(Whh0 + c * 1024 + k0);
    }
  } else if (wave == 2) {
#pragma unroll
    for (int f = 0; f < 32; ++f) {
      int k0 = f * 32 + kg * 8;
      bw[f] = ldw8(Wih1 + c * 1024 + k0);
    }
    bias = bih1[c] + bhh1[c];
  } else {
#pragma unroll
    for (int f = 0; f < 32; ++f) {
      int k0 = f * 32 + kg * 8;
      bw[f] = ldw8(Whh1 + c * 1024 + k0);
    }
  }

  for (int s = 0; s < STEPS; ++s) {
    const bool l1act = (s < T_STEPS);   // computes h1[s]
    const bool l2act = (s >= 1);        // computes h2[s-1] from r1[s-1], h2[s-2]
    const _Float16* h1rd = h1b + (size_t)(((s + 1) & 1) * 4 + g) * 16384;  // h1[s-1]
    const _Float16* h2rd = h2b + (size_t)(((s) & 1) * 4 + g) * 16384;      // h2[s-2]
    _Float16* h1wr = h1b + (size_t)(((s) & 1) * 4 + g) * 16384;            // h1[s]
    _Float16* h2wr = h2b + (size_t)(((s + 1) & 1) * 4 + g) * 16384;        // h2[s-1]

    f32x4 acc = {0.f, 0.f, 0.f, 0.f};
    if (wave == 0) {
      if (l1act) {
        const _Float16* xsrc = xt + (size_t)(s * 4 + g) * 1024;
#pragma unroll
        for (int f = 0; f < 17; ++f) {
          half8 a = (f < 2) ? *(const half8*)(xsrc + f * 512 + lane * 8)
                            : ldh8_coh(h1rd + (f - 2) * 512 + lane * 8);
          acc = __builtin_amdgcn_mfma_f32_16x16x32_f16(a, bw[f], acc, 0, 0, 0);
        }
      }
    } else if (wave == 1) {
      if (l1act) {
#pragma unroll
        for (int f = 0; f < 17; ++f) {
          half8 a = ldh8_coh(h1rd + (f + 15) * 512 + lane * 8);
          acc = __builtin_amdgcn_mfma_f32_16x16x32_f16(a, bw[f], acc, 0, 0, 0);
        }
#pragma unroll
        for (int r = 0; r < 4; ++r) pcL1[(kg * 4 + r) * 16 + col] = acc[r];
      }
    } else if (wave == 2) {
      if (l2act) {
#pragma unroll
        for (int f = 0; f < 32; ++f) {
          half8 a = ldh8_coh(h1rd + f * 512 + lane * 8);
          acc = __builtin_amdgcn_mfma_f32_16x16x32_f16(a, bw[f], acc, 0, 0, 0);
        }
      }
    } else {
      if (l2act) {
#pragma unroll
        for (int f = 0; f < 32; ++f) {
          half8 a = ldh8_coh(h2rd + f * 512 + lane * 8);
          acc = __builtin_amdgcn_mfma_f32_16x16x32_f16(a, bw[f], acc, 0, 0, 0);
        }
#pragma unroll
        for (int r = 0; r < 4; ++r) pcL2[(kg * 4 + r) * 16 + col] = acc[r];
      }
    }
    __syncthreads();

    if (wave == 0 && l1act) {
#pragma unroll
      for (int r = 0; r < 4; ++r) {
        int row = kg * 4 + r;
        float z = acc[r] + pcL1[row * 16 + col] + bias;
        float h = tanh_fast(z);
        sth_coh(h1wr + ((cu * 2 + (col >> 3)) * 16 + row) * 8 + (col & 7), h);
        if (s == T_STEPS - 1) out[64 + (g * 16 + row) * 1024 + c] = h;  // h_new[0]
      }
    }
    if (wave == 2 && l2act) {
#pragma unroll
      for (int r = 0; r < 4; ++r) {
        int row = kg * 4 + r;
        float z = acc[r] + pcL2[row * 16 + col] + bias;
        float h = tanh_fast(z);
        sth_coh(h2wr + ((cu * 2 + (col >> 3)) * 16 + row) * 8 + (col & 7), h);
        if (s == 1)   // r2[:,0,:] for the projection, f32, coherent
          __hip_atomic_store((unsigned*)(h2t0 + (size_t)(g * 16 + row) * 1024 + c),
                             __float_as_uint(h), __ATOMIC_RELAXED,
                             __HIP_MEMORY_SCOPE_AGENT);
        if (s == STEPS - 1) out[64 + 65536 + (g * 16 + row) * 1024 + c] = h;  // h_new[1]
      }
    }
    // barrier #2: compiler emits vmcnt(0)+s_barrier -> ALL waves' write-through
    // (sc0 sc1) h stores are committed at the coherence point before tid0 signals.
    __syncthreads();

    // ---- fence-free group barrier: parallel flag stores + 64-lane gather-poll ----
    // Flags monotonic (store s+1, poll >= s+1). Bounded spin: deadlock degrades
    // to wrong-answer, never a hung container.
    if (tid == 0)
      __hip_atomic_store(flags + (size_t)(g * 64 + cu) * 16, (unsigned)(s + 1),
                         __ATOMIC_RELAXED, __HIP_MEMORY_SCOPE_AGENT);
    if (tid < 64) {
      unsigned* f = flags + (size_t)(g * 64 + tid) * 16;
      unsigned spins = 0;
      while (__hip_atomic_load(f, __ATOMIC_RELAXED, __HIP_MEMORY_SCOPE_AGENT) <
             (unsigned)(s + 1)) {
        __builtin_amdgcn_s_sleep(1);
        if (++spins > (1u << 20)) break;   // safety valve
      }
    }
    __syncthreads();   // pollers done; next step's coherent loads issue after this
  }

  // out = r2[:,0,:] @ W_out^T + b_out  (leader WG of each group: its 16 batches)
  if (cu == 0) {
    const int b = tid >> 4, seg = tid & 15;
    const float* hrow = h2t0 + (size_t)(g * 16 + b) * 1024 + seg * 64;
    const float* wrow = Wout + seg * 64;
    float sum = 0.f;
#pragma unroll
    for (int i = 0; i < 64; ++i) {
      unsigned u = __hip_atomic_load((unsigned*)(hrow + i), __ATOMIC_RELAXED,
                                     __HIP_MEMORY_SCOPE_AGENT);
      sum += __uint_as_float(u) * wrow[i];
    }
    sum += __shfl_xor(sum, 1);
    sum += __shfl_xor(sum, 2);
    sum += __shfl_xor(sum, 4);
    sum += __shfl_xor(sum, 8);
    if (seg == 0) out[g * 16 + b] = sum + bout[0];
  }
}

extern "C" void kernel_launch(void* const* d_in, const int* in_sizes, int n_in,
                              void* d_out, int out_size, void* d_ws, size_t ws_size,
                              hipStream_t stream) {
  const float* x    = (const float*)d_in[0];
  const float* hs   = (const float*)d_in[1];
  const float* Wih0 = (const float*)d_in[2];
  const float* Whh0 = (const float*)d_in[3];
  const float* bih0 = (const float*)d_in[4];
  const float* bhh0 = (const float*)d_in[5];
  const float* Wih1 = (const float*)d_in[6];
  const float* Whh1 = (const float*)d_in[7];
  const float* bih1 = (const float*)d_in[8];
  const float* bhh1 = (const float*)d_in[9];
  const float* Wout = (const float*)d_in[10];
  const float* bout = (const float*)d_in[11];
  float* out = (float*)d_out;
  char* ws = (char*)d_ws;

  _Float16* xt  = (_Float16*)(ws + XT_OFF);
  _Float16* h1b = (_Float16*)(ws + H1_OFF);
  _Float16* h2b = (_Float16*)(ws + H2_OFF);

  prep_x<<<8192, 256, 0, stream>>>(x, xt);
  prep_h<<<512, 256, 0, stream>>>(hs, h1b, h2b, ws);
  rnn_persist<<<256, 256, 0, stream>>>(Wih0, Whh0, bih0, bhh0,
                                       Wih1, Whh1, bih1, bhh1,
                                       Wout, bout, out, ws);
}

// Round 12
// 2294.510 us; speedup vs baseline: 2.6570x; 1.1221x over previous
//
#include <hip/hip_runtime.h>
#include <hip/hip_bf16.h>

// RNN_46548855554081: 2-layer tanh RNN, B=64, T=512, H=1024, IN=64, OUT=1.
// R12: cut coherence-point READ traffic 3x. R11 (fence-free, 2575us) left
// ~2.5us/step of coherent h-read stream: 256 WGs x 96KB = 24.6 MB/step (64x
// broadcast amplification). Now: 512-thr WGs (2 quads x 4 wave-roles), 32
// WGs/group, and h1+h2 staged into LDS ONCE per WG (64KB cooperative coherent
// burst) -> MFMA frags read LDS. 8 MB/step. Write-through h + flag barrier
// (parallel stores + gather-poll) unchanged from R11 (absmax 1.95e-3).

typedef float f32x4 __attribute__((ext_vector_type(4)));
typedef _Float16 half8 __attribute__((ext_vector_type(8)));

#define T_STEPS 512
#define STEPS 513

// ws layout (bytes)
#define CTR_OFF   0                        // 128 flag slots x 64B (prep zeroes 16KB)
#define XT_OFF    16384                    // [512][4][8kg][16row][8] f16 = 4 MB
#define H1_OFF    (XT_OFF + 4194304)       // [2buf][4g][128kg][16row][8] f16 = 256 KB
#define H2_OFF    (H1_OFF + 262144)        // same, 256 KB
#define H2T0_OFF  (H2_OFF + 262144)        // [64][1024] f32 = 256 KB (h2 at t=0)

__device__ inline float tanh_fast(float z) {
  z = fminf(20.f, fmaxf(-20.f, z));
  float e = __expf(2.f * z);
  return (e - 1.f) / (e + 1.f);
}

__device__ inline half8 ldw8(const float* p) {
  half8 r;
#pragma unroll
  for (int i = 0; i < 8; ++i) r[i] = (_Float16)p[i];
  return r;
}

// coherent (agent-scope, relaxed) 16B fragment load: 2 x u64 atomic loads
__device__ inline half8 ldh8_coh(const _Float16* p) {
  union { unsigned long long q[2]; half8 h; } u;
  unsigned long long* a = (unsigned long long*)p;
  u.q[0] = __hip_atomic_load(a,     __ATOMIC_RELAXED, __HIP_MEMORY_SCOPE_AGENT);
  u.q[1] = __hip_atomic_load(a + 1, __ATOMIC_RELAXED, __HIP_MEMORY_SCOPE_AGENT);
  return u.h;
}

// coherent 2B h-element store
__device__ inline void sth_coh(_Float16* p, float v) {
  union { _Float16 h; unsigned short u; } cv;
  cv.h = (_Float16)v;
  __hip_atomic_store((unsigned short*)p, cv.u, __ATOMIC_RELAXED, __HIP_MEMORY_SCOPE_AGENT);
}

// ---- prep: tile x into f16 fragment layout [t][g][kg(8)][16row][8] ----
__global__ void prep_x(const float* __restrict__ x, _Float16* __restrict__ xt) {
  int i = blockIdx.x * 256 + threadIdx.x;       // 2^21 elements
  int j = i & 7;
  int row = (i >> 3) & 15;
  int kgv = (i >> 7) & 7;
  int gg = (i >> 10) & 3;
  int t = i >> 12;
  int b = gg * 16 + row;
  xt[i] = (_Float16)x[(b * 512 + t) * 64 + kgv * 8 + j];
}

// ---- prep: tile h_state into h buffers (buf index 1), zero barrier flags ----
__global__ void prep_h(const float* __restrict__ hs, _Float16* __restrict__ h1b,
                       _Float16* __restrict__ h2b, char* __restrict__ wsbase) {
  int i = blockIdx.x * 256 + threadIdx.x;       // 2^17 elements
  int j = i & 7;
  int row = (i >> 3) & 15;
  int kgv = (i >> 7) & 127;
  int gg = (i >> 14) & 3;
  int l = i >> 16;
  int b = gg * 16 + row;
  int h = kgv * 8 + j;
  float v = hs[(size_t)l * 65536 + b * 1024 + h];
  _Float16* dst = l ? h2b : h1b;
  dst[(size_t)(4 + gg) * 16384 + (kgv * 16 + row) * 8 + j] = (_Float16)v;
  if (i < 256) *(unsigned*)(wsbase + CTR_OFF + (size_t)i * 64) = 0u;
}

// ---- persistent pipelined scan: 128 WGs x 512 thr (2 quads x 4 wave roles) ----
__global__ __launch_bounds__(512, 1) void rnn_persist(
    const float* __restrict__ Wih0, const float* __restrict__ Whh0,
    const float* __restrict__ bih0, const float* __restrict__ bhh0,
    const float* __restrict__ Wih1, const float* __restrict__ Whh1,
    const float* __restrict__ bih1, const float* __restrict__ bhh1,
    const float* __restrict__ Wout, const float* __restrict__ bout,
    float* __restrict__ out, char* __restrict__ ws) {
  __shared__ _Float16 h1s[16384];   // group h1[s-1], fragment-tiled (32 KB)
  __shared__ _Float16 h2s[16384];   // group h2[s-2], fragment-tiled (32 KB)
  __shared__ float pcL1[2][256];
  __shared__ float pcL2[2][256];

  const int bid = blockIdx.x;
  const int g = bid >> 5;          // batch group (16 batches)
  const int wgi = bid & 31;        // WG within group; owns cols [32*wgi, 32*wgi+32)
  const int tid = threadIdx.x;
  const int quad = tid >> 8;       // 0..1: independent 16-col unit
  const int wq = (tid >> 6) & 3;   // wave role within quad
  const int lane = tid & 63;
  const int col = lane & 15;
  const int kg = lane >> 4;        // k-subgroup within fragment / row-group in C

  unsigned* flags = (unsigned*)(ws + CTR_OFF);   // slot (g*32+wgi), 64B stride
  const _Float16* xt = (const _Float16*)(ws + XT_OFF);
  _Float16* h1b = (_Float16*)(ws + H1_OFF);
  _Float16* h2b = (_Float16*)(ws + H2_OFF);
  float* h2t0 = (float*)(ws + H2T0_OFF);

  const int cu = wgi * 2 + quad;   // 16-col tile index, 0..63
  const int c = cu * 16 + col;     // output column for this lane

  // ---- weights -> f16 register fragments (once); per quad, 4-role split:
  // wq0: L1 K[0,544) (x part K<64, then W_hh0); wq1: L1 K[544,1088)
  // wq2: L2 K[0,1024) = W_ih1;                  wq3: L2 K[1024,2048) = W_hh1
  half8 bw[32];
  float bias = 0.f;
  if (wq == 0) {
#pragma unroll
    for (int f = 0; f < 17; ++f) {
      int k0 = f * 32 + kg * 8;
      const float* p = (k0 < 64) ? (Wih0 + c * 64 + k0) : (Whh0 + c * 1024 + (k0 - 64));
      bw[f] = ldw8(p);
    }
    bias = bih0[c] + bhh0[c];
  } else if (wq == 1) {
#pragma unroll
    for (int f = 0; f < 17; ++f) {
      int k0 = (f + 17) * 32 + kg * 8 - 64;   // [480, 1024)
      bw[f] = ldw8(Whh0 + c * 1024 + k0);
    }
  } else if (wq == 2) {
#pragma unroll
    for (int f = 0; f < 32; ++f) {
      int k0 = f * 32 + kg * 8;
      bw[f] = ldw8(Wih1 + c * 1024 + k0);
    }
    bias = bih1[c] + bhh1[c];
  } else {
#pragma unroll
    for (int f = 0; f < 32; ++f) {
      int k0 = f * 32 + kg * 8;
      bw[f] = ldw8(Whh1 + c * 1024 + k0);
    }
  }

  for (int s = 0; s < STEPS; ++s) {
    const bool l1act = (s < T_STEPS);   // computes h1[s]
    const bool l2act = (s >= 1);        // computes h2[s-1] from r1[s-1], h2[s-2]
    const _Float16* h1rd = h1b + (size_t)(((s + 1) & 1) * 4 + g) * 16384;  // h1[s-1]
    const _Float16* h2rd = h2b + (size_t)(((s) & 1) * 4 + g) * 16384;      // h2[s-2]
    _Float16* h1wr = h1b + (size_t)(((s) & 1) * 4 + g) * 16384;            // h1[s]
    _Float16* h2wr = h2b + (size_t)(((s + 1) & 1) * 4 + g) * 16384;        // h2[s-1]

    // ---- cooperative coherent stage: group h1[s-1], h2[s-2] -> LDS ----
    // 64 KB per WG per step (vs 96 KB of duplicated per-wave reads in R11);
    // one pipelined burst of 8x16B coherent loads per thread. (h2 garbage at
    // s=0 and h1 stale at s=512 are staged but never consumed - guards below.)
#pragma unroll
    for (int it = 0; it < 4; ++it)
      *(half8*)&h1s[(it * 512 + tid) * 8] = ldh8_coh(h1rd + (size_t)(it * 512 + tid) * 8);
#pragma unroll
    for (int it = 0; it < 4; ++it)
      *(half8*)&h2s[(it * 512 + tid) * 8] = ldh8_coh(h2rd + (size_t)(it * 512 + tid) * 8);
    __syncthreads();

    f32x4 acc = {0.f, 0.f, 0.f, 0.f};
    if (wq == 0) {
      if (l1act) {
        const _Float16* xsrc = xt + (size_t)(s * 4 + g) * 1024;
#pragma unroll
        for (int f = 0; f < 17; ++f) {
          half8 a = (f < 2) ? *(const half8*)(xsrc + f * 512 + lane * 8)
                            : *(const half8*)&h1s[(f - 2) * 512 + lane * 8];
          acc = __builtin_amdgcn_mfma_f32_16x16x32_f16(a, bw[f], acc, 0, 0, 0);
        }
      }
    } else if (wq == 1) {
      if (l1act) {
#pragma unroll
        for (int f = 0; f < 17; ++f) {
          half8 a = *(const half8*)&h1s[(f + 15) * 512 + lane * 8];
          acc = __builtin_amdgcn_mfma_f32_16x16x32_f16(a, bw[f], acc, 0, 0, 0);
        }
#pragma unroll
        for (int r = 0; r < 4; ++r) pcL1[quad][(kg * 4 + r) * 16 + col] = acc[r];
      }
    } else if (wq == 2) {
      if (l2act) {
#pragma unroll
        for (int f = 0; f < 32; ++f) {
          half8 a = *(const half8*)&h1s[f * 512 + lane * 8];
          acc = __builtin_amdgcn_mfma_f32_16x16x32_f16(a, bw[f], acc, 0, 0, 0);
        }
      }
    } else {
      if (l2act) {
#pragma unroll
        for (int f = 0; f < 32; ++f) {
          half8 a = *(const half8*)&h2s[f * 512 + lane * 8];
          acc = __builtin_amdgcn_mfma_f32_16x16x32_f16(a, bw[f], acc, 0, 0, 0);
        }
#pragma unroll
        for (int r = 0; r < 4; ++r) pcL2[quad][(kg * 4 + r) * 16 + col] = acc[r];
      }
    }
    __syncthreads();

    if (wq == 0 && l1act) {
#pragma unroll
      for (int r = 0; r < 4; ++r) {
        int row = kg * 4 + r;
        float z = acc[r] + pcL1[quad][row * 16 + col] + bias;
        float h = tanh_fast(z);
        sth_coh(h1wr + ((cu * 2 + (col >> 3)) * 16 + row) * 8 + (col & 7), h);
        if (s == T_STEPS - 1) out[64 + (g * 16 + row) * 1024 + c] = h;  // h_new[0]
      }
    }
    if (wq == 2 && l2act) {
#pragma unroll
      for (int r = 0; r < 4; ++r) {
        int row = kg * 4 + r;
        float z = acc[r] + pcL2[quad][row * 16 + col] + bias;
        float h = tanh_fast(z);
        sth_coh(h2wr + ((cu * 2 + (col >> 3)) * 16 + row) * 8 + (col & 7), h);
        if (s == 1)   // r2[:,0,:] for the projection, f32, coherent
          __hip_atomic_store((unsigned*)(h2t0 + (size_t)(g * 16 + row) * 1024 + c),
                             __float_as_uint(h), __ATOMIC_RELAXED,
                             __HIP_MEMORY_SCOPE_AGENT);
        if (s == STEPS - 1) out[64 + 65536 + (g * 16 + row) * 1024 + c] = h;  // h_new[1]
      }
    }
    // compiler emits vmcnt(0)+s_barrier: ALL waves' write-through h stores are
    // committed at the coherence point before tid0 signals.
    __syncthreads();

    // ---- fence-free group barrier: parallel flag stores + 32-lane gather-poll ----
    if (tid == 0)
      __hip_atomic_store(flags + (size_t)(g * 32 + wgi) * 16, (unsigned)(s + 1),
                         __ATOMIC_RELAXED, __HIP_MEMORY_SCOPE_AGENT);
    if (tid < 32) {
      unsigned* f = flags + (size_t)(g * 32 + tid) * 16;
      unsigned spins = 0;
      while (__hip_atomic_load(f, __ATOMIC_RELAXED, __HIP_MEMORY_SCOPE_AGENT) <
             (unsigned)(s + 1)) {
        __builtin_amdgcn_s_sleep(1);
        if (++spins > (1u << 20)) break;   // safety valve
      }
    }
    __syncthreads();   // pollers done; next step's staging loads issue after this
  }

  // out = r2[:,0,:] @ W_out^T + b_out  (leader WG of each group: its 16 batches)
  if (wgi == 0 && tid < 256) {
    const int b = tid >> 4, seg = tid & 15;
    const float* hrow = h2t0 + (size_t)(g * 16 + b) * 1024 + seg * 64;
    const float* wrow = Wout + seg * 64;
    float sum = 0.f;
#pragma unroll
    for (int i = 0; i < 64; ++i) {
      unsigned u = __hip_atomic_load((unsigned*)(hrow + i), __ATOMIC_RELAXED,
                                     __HIP_MEMORY_SCOPE_AGENT);
      sum += __uint_as_float(u) * wrow[i];
    }
    sum += __shfl_xor(sum, 1);
    sum += __shfl_xor(sum, 2);
    sum += __shfl_xor(sum, 4);
    sum += __shfl_xor(sum, 8);
    if (seg == 0) out[g * 16 + b] = sum + bout[0];
  }
}

extern "C" void kernel_launch(void* const* d_in, const int* in_sizes, int n_in,
                              void* d_out, int out_size, void* d_ws, size_t ws_size,
                              hipStream_t stream) {
  const float* x    = (const float*)d_in[0];
  const float* hs   = (const float*)d_in[1];
  const float* Wih0 = (const float*)d_in[2];
  const float* Whh0 = (const float*)d_in[3];
  const float* bih0 = (const float*)d_in[4];
  const float* bhh0 = (const float*)d_in[5];
  const float* Wih1 = (const float*)d_in[6];
  const float* Whh1 = (const float*)d_in[7];
  const float* bih1 = (const float*)d_in[8];
  const float* bhh1 = (const float*)d_in[9];
  const float* Wout = (const float*)d_in[10];
  const float* bout = (const float*)d_in[11];
  float* out = (float*)d_out;
  char* ws = (char*)d_ws;

  _Float16* xt  = (_Float16*)(ws + XT_OFF);
  _Float16* h1b = (_Float16*)(ws + H1_OFF);
  _Float16* h2b = (_Float16*)(ws + H2_OFF);

  prep_x<<<8192, 256, 0, stream>>>(x, xt);
  prep_h<<<512, 256, 0, stream>>>(hs, h1b, h2b, ws);
  rnn_persist<<<128, 512, 0, stream>>>(Wih0, Whh0, bih0, bhh0,
                                       Wih1, Whh1, bih1, bhh1,
                                       Wout, bout, out, ws);
}